// Round 5
// baseline (111.464 us; speedup 1.0000x reference)
//
#include <hip/hip_runtime.h>

#define BB 8
#define NN 256
#define FDIM 1024
#define HDIM 256
#define NSQ 65536            // NN*NN
#define ROWS 2048            // BB*NN
#define KSEL 39321           // int(0.6*NN*NN)
#define NBIN 8192            // 13-bit fkey bins

typedef short s16x8 __attribute__((ext_vector_type(8)));
typedef float f32x4 __attribute__((ext_vector_type(4)));
typedef float f32x2 __attribute__((ext_vector_type(2)));

// ---------- helpers ----------
__device__ __forceinline__ unsigned fkey(float f) {
  unsigned u = __float_as_uint(f);
  return (u & 0x80000000u) ? ~u : (u | 0x80000000u);
}
__device__ __forceinline__ float finv(unsigned k) {
  unsigned u = (k & 0x80000000u) ? (k & 0x7fffffffu) : ~k;
  return __uint_as_float(u);
}
__device__ __forceinline__ unsigned short f2bf(float f) {   // RNE
  unsigned u = __float_as_uint(f);
  unsigned r = (u + 0x7fffu + ((u >> 16) & 1u)) >> 16;
  return (unsigned short)r;
}
__device__ __forceinline__ void gl_lds16(const unsigned short* g, unsigned short* l) {
  __builtin_amdgcn_global_load_lds(
      (const __attribute__((address_space(1))) unsigned int*)(g),
      (__attribute__((address_space(3))) unsigned int*)(l), 16, 0, 0);
}

// ---------- K0: convert X,W1 -> bf16 + zero gcount/gvsum ----------
// grid 1408: [0,1024) X, [1024,1280) W1, [1280,1408) zero (131072 words).
__global__ __launch_bounds__(256) void k_prep(const float* __restrict__ X,
                                              const float* __restrict__ W1,
                                              unsigned short* __restrict__ XB,
                                              unsigned short* __restrict__ W1B,
                                              unsigned* __restrict__ zero) {
  const int bx = blockIdx.x, t = threadIdx.x;
  if (bx < 1280) {
    const float* src = (bx < 1024) ? X : W1;
    unsigned short* dst = (bx < 1024) ? XB : W1B;
    const int idx = ((bx < 1024 ? bx : bx - 1024) * 256 + t) * 8;
    float4 v0 = *(const float4*)&src[idx];
    float4 v1 = *(const float4*)&src[idx + 4];
    s16x8 o;
    o[0] = (short)f2bf(v0.x); o[1] = (short)f2bf(v0.y); o[2] = (short)f2bf(v0.z); o[3] = (short)f2bf(v0.w);
    o[4] = (short)f2bf(v1.x); o[5] = (short)f2bf(v1.y); o[6] = (short)f2bf(v1.z); o[7] = (short)f2bf(v1.w);
    *(s16x8*)&dst[idx] = o;
  } else {
    const int idx = ((bx - 1280) * 256 + t) * 4;
    *(uint4*)&zero[idx] = make_uint4(0u, 0u, 0u, 0u);
  }
}

// ---------- K1: bf16-MFMA GEMM, 64m x 32n tiles, grid (32,16) = 512 blocks ----------
// global_load_lds(16B) staging into double-buffered, XOR-swizzled linear LDS:
// store: LDS dest linear, source col pre-swizzled (col_bytes ^= (row&7)<<4);
// read : same XOR on the ds_read address (rule: both-sides-or-neither).
// 6 ds_read + 0 ds_write per wave per K-step (was 6+3). 2 blocks/CU, 8 waves.
// PRBT[h][row] = (x@Wr^T + b1)^T ; PCT[h][row] = (x@Wc^T)^T, row = b*256+n.
__global__ __launch_bounds__(256) void k_gemm(const unsigned short* __restrict__ XB,
                                              const unsigned short* __restrict__ W1B,
                                              const float* __restrict__ b1,
                                              float* __restrict__ PRBT,
                                              float* __restrict__ PCT) {
  const int bm = blockIdx.x * 64;
  const int bn = blockIdx.y * 32;          // 0..480
  const int t = threadIdx.x;
  __shared__ unsigned short As[2][4096];   // 64 rows x 64 cols (swizzled)
  __shared__ unsigned short Bs[2][2048];   // 32 rows x 64 cols (swizzled)
  const int w = t >> 6, lane = t & 63;
  const int l3 = lane >> 3, l7 = lane & 7;
  const int csw = (l7 ^ l3) * 8;           // pre-swizzled col offset (shorts)
  // staging rows: A issue i: row = i*32 + w*8 + l3 ; B: row = w*8 + l3
  const unsigned short* srcA0 = XB + (bm + w * 8 + l3) * FDIM + csw;
  const unsigned short* srcA1 = XB + (bm + 32 + w * 8 + l3) * FDIM + csw;
  const int rowB = w * 8 + l3;
  const unsigned short* srcB = (bn < 256)
      ? (W1B + (bn + rowB) * (2 * FDIM) + csw)
      : (W1B + (bn - 256 + rowB) * (2 * FDIM) + FDIM + csw);
  const int dst = w * 512 + lane * 8;      // linear LDS dest (shorts)
  const int wm = (w & 1) * 32, wn = (w >> 1) * 16;   // 4 waves cover 64m x 32n
  const int q = lane >> 4, m16 = lane & 15;
  const int x7 = m16 & 7;                  // read-side XOR term
  f32x4 acc[2] = {};
  // prologue: stage K-step 0 into buf 0
  gl_lds16(srcA0, &As[0][dst]);
  gl_lds16(srcA1, &As[0][2048 + dst]);
  gl_lds16(srcB,  &Bs[0][dst]);
  __syncthreads();                         // implicit vmcnt(0) drains DMA
  int cur = 0;
  for (int k0 = 0; k0 < FDIM; k0 += 64) {
    if (k0 + 64 < FDIM) {                  // stage next K-step (overlaps MFMA)
      gl_lds16(srcA0 + k0 + 64, &As[cur ^ 1][dst]);
      gl_lds16(srcA1 + k0 + 64, &As[cur ^ 1][2048 + dst]);
      gl_lds16(srcB  + k0 + 64, &Bs[cur ^ 1][dst]);
    }
#pragma unroll
    for (int koff = 0; koff < 64; koff += 32) {
      const int soff = ((((koff >> 5) * 4 + q) ^ x7)) * 8;   // swizzled slot
      s16x8 af0 = *(s16x8*)&As[cur][(wm + m16) * 64 + soff];
      s16x8 af1 = *(s16x8*)&As[cur][(wm + 16 + m16) * 64 + soff];
      s16x8 bf0 = *(s16x8*)&Bs[cur][(wn + m16) * 64 + soff];
      acc[0] = __builtin_amdgcn_mfma_f32_16x16x32_bf16(af0, bf0, acc[0], 0, 0, 0);
      acc[1] = __builtin_amdgcn_mfma_f32_16x16x32_bf16(af1, bf0, acc[1], 0, 0, 0);
    }
    __syncthreads();                       // drains next-buf DMA + guards reuse
    cur ^= 1;
  }
  // epilogue: D map col(n)=lane&15, row(m)=q*4+reg; rows contiguous in PRBT/PCT
#pragma unroll
  for (int rt = 0; rt < 2; ++rt) {
    const int hn = bn + wn + m16;          // 0..511
    const int row0 = bm + wm + rt * 16 + q * 4;
    if (hn < 256) {
      const float bias = b1[hn];
      float4 v = make_float4(acc[rt][0] + bias, acc[rt][1] + bias,
                             acc[rt][2] + bias, acc[rt][3] + bias);
      *(float4*)&PRBT[hn * ROWS + row0] = v;
    } else {
      float4 v = make_float4(acc[rt][0], acc[rt][1], acc[rt][2], acc[rt][3]);
      *(float4*)&PCT[(hn - 256) * ROWS + row0] = v;
    }
  }
}

// ---------- K2: edge + 13-bit count/value histogram ----------
// tile 64(i) x 32(j), 512 threads (8 waves/CU), 2x2 per thread; grid 256.
// Inner loop on f32x2 -> v_pk_add_f32 / v_pk_fma_f32 (8 VALU instrs / 4 cells).
__global__ __launch_bounds__(512) void k_edge(const float* __restrict__ PRBT,
                                              const float* __restrict__ PCT,
                                              const float* __restrict__ W2,
                                              const float* __restrict__ b2,
                                              float* __restrict__ edge,
                                              unsigned* __restrict__ gcount,
                                              float* __restrict__ gvsum) {
  const int b = blockIdx.z;
  const int i0 = blockIdx.y * 64, j0 = blockIdx.x * 32;
  const int t = threadIdx.x;
  __shared__ float prs[64][68];        // [h][i]
  __shared__ float pcs[64][36];        // [h][j]
  __shared__ float w2s[HDIM];
  __shared__ unsigned lhc[NBIN / 2];   // packed 2x16-bit counts (16 KB)
  __shared__ float lhv[NBIN];          // value sums (32 KB)
  if (t < HDIM) w2s[t] = W2[t];
#pragma unroll
  for (int i = 0; i < 2; ++i) ((uint4*)lhc)[t + i * 512] = make_uint4(0u, 0u, 0u, 0u);
#pragma unroll
  for (int i = 0; i < 4; ++i) ((float4*)lhv)[t + i * 512] = make_float4(0.f, 0.f, 0.f, 0.f);
  const float bias = b2[0];
  const int tmi = t >> 4, tnj = t & 15;     // i-pair 0..31, j-pair 0..15
  f32x2 acc0 = {0.f, 0.f};                  // row ibase   : (j, j+1)
  f32x2 acc1 = {0.f, 0.f};                  // row ibase+1 : (j, j+1)
  for (int h0 = 0; h0 < HDIM; h0 += 64) {
    __syncthreads();
#pragma unroll
    for (int s = 0; s < 2; ++s) {           // prs: 64h x 64i (1024 float4)
      int idx = t + s * 512;
      int hh = idx >> 4, ig = idx & 15;
      *(float4*)&prs[hh][ig * 4] =
          *(const float4*)&PRBT[(h0 + hh) * ROWS + b * NN + i0 + ig * 4];
    }
    {                                       // pcs: 64h x 32j (512 float4)
      int hh = t >> 3, jg = t & 7;
      *(float4*)&pcs[hh][jg * 4] =
          *(const float4*)&PCT[(h0 + hh) * ROWS + b * NN + j0 + jg * 4];
    }
    __syncthreads();
#pragma unroll 8
    for (int h = 0; h < 64; ++h) {
      const float w = w2s[h0 + h];
      const f32x2 a = *(const f32x2*)&prs[h][tmi * 2];
      const f32x2 c = *(const f32x2*)&pcs[h][tnj * 2];
      f32x2 x0 = c + a.x;                   // pk_add
      f32x2 x1 = c + a.y;
      x0.x = fmaxf(x0.x, 0.f); x0.y = fmaxf(x0.y, 0.f);
      x1.x = fmaxf(x1.x, 0.f); x1.y = fmaxf(x1.y, 0.f);
      acc0 += x0 * w;                       // pk_fma
      acc1 += x1 * w;
    }
  }
  // write edge + histogram (values in registers)
  const int ibase = i0 + tmi * 2, jbase = j0 + tnj * 2;
  float av[2][2] = {{acc0.x, acc0.y}, {acc1.x, acc1.y}};
#pragma unroll
  for (int i = 0; i < 2; ++i) {
    float2 v = make_float2(av[i][0] + bias, av[i][1] + bias);
    *(float2*)&edge[b * NSQ + (ibase + i) * NN + jbase] = v;
    float ex = __expf(v.x * 2.f), ey = __expf(v.y * 2.f);
    unsigned bx = fkey(v.x) >> 19, by = fkey(v.y) >> 19;
    atomicAdd(&lhc[bx >> 1], 1u << ((bx & 1) * 16));
    atomicAdd(&lhv[bx], ex);
    atomicAdd(&lhc[by >> 1], 1u << ((by & 1) * 16));
    atomicAdd(&lhv[by], ey);
  }
  __syncthreads();
  unsigned* gc = gcount + b * NBIN;
  float* gv = gvsum + b * NBIN;
#pragma unroll
  for (int i = 0; i < 8; ++i) {
    const int idx = t + i * 512;
    unsigned wv = lhc[idx];
    if (wv) {
      unsigned lo = wv & 0xFFFFu, hi = wv >> 16;
      if (lo) atomicAdd(&gc[2 * idx], lo);
      if (hi) atomicAdd(&gc[2 * idx + 1], hi);
    }
  }
#pragma unroll
  for (int i = 0; i < 16; ++i) {
    const int idx = t + i * 512;
    float vv = lhv[idx];
    if (vv != 0.f) atomicAdd(&gv[idx], vv);
  }
}

// ---------- K3: scan (inline) + soft + causal + conf ----------
__global__ __launch_bounds__(256) void k_out(const float* __restrict__ edge,
                                             const unsigned* __restrict__ gcount,
                                             const float* __restrict__ gvsum,
                                             float* __restrict__ soft,
                                             float* __restrict__ causal,
                                             float* __restrict__ conf) {
  const int b = blockIdx.y;
  const int t = threadIdx.x;
  __shared__ unsigned S[256];
  __shared__ float V[256];
  __shared__ unsigned ou[1];
  __shared__ float of[3];
  const unsigned* hc = gcount + b * NBIN;
  const float* hv = gvsum + b * NBIN;
  unsigned cs = 0; float vs = 0.f;
  {
    const uint4* hc4 = (const uint4*)(hc + t * 32);
    const float4* hv4 = (const float4*)(hv + t * 32);
#pragma unroll
    for (int i = 0; i < 8; ++i) {
      uint4 c = hc4[i];
      float4 v = hv4[i];
      cs += c.x + c.y + c.z + c.w;
      vs += v.x + v.y + v.z + v.w;
    }
  }
  S[t] = cs; V[t] = vs;
  __syncthreads();
  for (int off = 1; off < 256; off <<= 1) {     // inclusive suffix sums
    unsigned su = (t + off < 256) ? S[t + off] : 0u;
    float vu = (t + off < 256) ? V[t + off] : 0.f;
    __syncthreads();
    S[t] += su; V[t] += vu;
    __syncthreads();
  }
  if (t == 0) of[2] = V[0];                      // Z = total exp sum
  const int above = (int)(S[t] - cs);
  if (above < KSEL && (int)S[t] >= KSEL) {       // exactly one thread
    int cum = above;
    float vcum = V[t] - vs;
    for (int i = 31; i >= 0; --i) {
      unsigned c = hc[t * 32 + i];
      float v = hv[t * 32 + i];
      cum += (int)c;
      if (cum >= KSEL) { ou[0] = (unsigned)(t * 32 + i); of[0] = vcum; of[1] = v; break; }
      vcum += v;
    }
  }
  __syncthreads();
  const float th = finv(ou[0] << 19);            // 13-bit truncated threshold
  const float Z = of[2];
  const float invZ = 1.f / Z;
  const float msum = (of[0] + of[1]) * invZ;     // masked soft sum (bin-exact)
  const float invD = 1.f / (msum + 1e-12f);
  const int off = b * NSQ + blockIdx.x * 2048 + t * 8;
#pragma unroll
  for (int i = 0; i < 8; i += 4) {
    float4 v = *(const float4*)&edge[off + i];
    float4 o = make_float4(__expf(v.x * 2.f) * invZ, __expf(v.y * 2.f) * invZ,
                           __expf(v.z * 2.f) * invZ, __expf(v.w * 2.f) * invZ);
    *(float4*)&soft[off + i] = o;
    float cx = v.x >= th ? o.x * invD : 0.f;
    float cy = v.y >= th ? o.y * invD : 0.f;
    float cz = v.z >= th ? o.z * invD : 0.f;
    float cw = v.w >= th ? o.w * invD : 0.f;
    *(float4*)&causal[off + i] = make_float4(cx, cy, cz, cw);
    *(float4*)&conf[off + i]   = make_float4(1.f - cx, 1.f - cy, 1.f - cz, 1.f - cw);
  }
}

extern "C" void kernel_launch(void* const* d_in, const int* in_sizes, int n_in,
                              void* d_out, int out_size, void* d_ws, size_t ws_size,
                              hipStream_t stream) {
  const float* x  = (const float*)d_in[0];
  const float* W1 = (const float*)d_in[1];
  const float* b1 = (const float*)d_in[2];
  const float* W2 = (const float*)d_in[3];
  const float* b2 = (const float*)d_in[4];

  float* out = (float*)d_out;
  float* causal = out;
  float* conf   = out + 1 * 524288;
  float* edge   = out + 2 * 524288;
  float* soft   = out + 3 * 524288;

  float* ws = (float*)d_ws;
  float*          PRBT   = ws;                                // 524288 floats
  float*          PCT    = ws + 524288;                       // 524288 floats
  unsigned short* XB     = (unsigned short*)(ws + 1048576);   // 2097152 bf16
  unsigned short* W1B    = (unsigned short*)(ws + 2097152);   // 524288 bf16
  unsigned*       gcount = (unsigned*)(ws + 2359296);         // 8*8192 uints
  float*          gvsum  = (float*)(ws + 2424832);            // 8*8192 floats (zero: 131072 words)

  k_prep<<<1408, 256, 0, stream>>>(x, W1, XB, W1B, gcount);
  k_gemm<<<dim3(32, 16), 256, 0, stream>>>(XB, W1B, b1, PRBT, PCT);
  k_edge<<<dim3(8, 4, 8), 512, 0, stream>>>(PRBT, PCT, W2, b2, edge, gcount, gvsum);
  k_out<<<dim3(32, 8), 256, 0, stream>>>(edge, gcount, gvsum, soft, causal, conf);
}

// Round 6
// 104.845 us; speedup vs baseline: 1.0631x; 1.0631x over previous
//
#include <hip/hip_runtime.h>

#define BB 8
#define NN 256
#define FDIM 1024
#define HDIM 256
#define NSQ 65536            // NN*NN
#define ROWS 2048            // BB*NN
#define KSEL 39321           // int(0.6*NN*NN)
#define NBIN 8192            // 13-bit fkey bins
#define LDSW 72              // gemm LDS row stride (bf16 elems)

typedef short s16x8 __attribute__((ext_vector_type(8)));
typedef float f32x4 __attribute__((ext_vector_type(4)));
typedef float f32x2 __attribute__((ext_vector_type(2)));

// ---------- helpers ----------
__device__ __forceinline__ unsigned fkey(float f) {
  unsigned u = __float_as_uint(f);
  return (u & 0x80000000u) ? ~u : (u | 0x80000000u);
}
__device__ __forceinline__ float finv(unsigned k) {
  unsigned u = (k & 0x80000000u) ? (k & 0x7fffffffu) : ~k;
  return __uint_as_float(u);
}
__device__ __forceinline__ unsigned short f2bf(float f) {   // RNE
  unsigned u = __float_as_uint(f);
  unsigned r = (u + 0x7fffu + ((u >> 16) & 1u)) >> 16;
  return (unsigned short)r;
}

// ---------- K0: convert X,W1 -> bf16 + zero gcount/gvsum ----------
// grid 1408: [0,1024) X, [1024,1280) W1, [1280,1408) zero (131072 words).
__global__ __launch_bounds__(256) void k_prep(const float* __restrict__ X,
                                              const float* __restrict__ W1,
                                              unsigned short* __restrict__ XB,
                                              unsigned short* __restrict__ W1B,
                                              unsigned* __restrict__ zero) {
  const int bx = blockIdx.x, t = threadIdx.x;
  if (bx < 1280) {
    const float* src = (bx < 1024) ? X : W1;
    unsigned short* dst = (bx < 1024) ? XB : W1B;
    const int idx = ((bx < 1024 ? bx : bx - 1024) * 256 + t) * 8;
    float4 v0 = *(const float4*)&src[idx];
    float4 v1 = *(const float4*)&src[idx + 4];
    s16x8 o;
    o[0] = (short)f2bf(v0.x); o[1] = (short)f2bf(v0.y); o[2] = (short)f2bf(v0.z); o[3] = (short)f2bf(v0.w);
    o[4] = (short)f2bf(v1.x); o[5] = (short)f2bf(v1.y); o[6] = (short)f2bf(v1.z); o[7] = (short)f2bf(v1.w);
    *(s16x8*)&dst[idx] = o;
  } else {
    const int idx = ((bx - 1280) * 256 + t) * 4;
    *(uint4*)&zero[idx] = make_uint4(0u, 0u, 0u, 0u);
  }
}

// ---------- K1: bf16-MFMA GEMM, 64m x 32n tiles, grid (32,16) = 512 blocks ----------
// 2 blocks/CU (LDS 13.8 KB) -> cross-block latency hiding. (round-0/3 proven version)
// PRBT[h][row] = (x@Wr^T + b1)^T ; PCT[h][row] = (x@Wc^T)^T, row = b*256+n.
__global__ __launch_bounds__(256) void k_gemm(const unsigned short* __restrict__ XB,
                                              const unsigned short* __restrict__ W1B,
                                              const float* __restrict__ b1,
                                              float* __restrict__ PRBT,
                                              float* __restrict__ PCT) {
  const int bm = blockIdx.x * 64;
  const int bn = blockIdx.y * 32;          // 0..480
  const int t = threadIdx.x;
  __shared__ short As[64 * LDSW];
  __shared__ short Bs[32 * LDSW];
  // A staging: row sr 0..63, 16-elem col group cg 0..3 (32 B/thread)
  const int sr = t >> 2, cg = t & 3;
  const unsigned short* pa = XB + (bm + sr) * FDIM + cg * 16;
  // B staging: row srb 0..31, 8-elem col group cgb 0..7 (16 B/thread)
  const int srb = t >> 3, cgb = t & 7;
  const unsigned short* pb = (bn < 256)
      ? (W1B + (bn + srb) * (2 * FDIM) + cgb * 8)
      : (W1B + (bn - 256 + srb) * (2 * FDIM) + FDIM + cgb * 8);
  const int w = t >> 6, lane = t & 63;
  const int wm = (w & 1) * 32, wn = (w >> 1) * 16;   // 4 waves cover 64m x 32n
  const int q = lane >> 4, m16 = lane & 15;
  f32x4 acc[2] = {};
  // prefetch iter 0
  s16x8 ra0 = *(const s16x8*)(pa);
  s16x8 ra1 = *(const s16x8*)(pa + 8);
  s16x8 rb = *(const s16x8*)(pb);
  for (int k0 = 0; k0 < FDIM; k0 += 64) {
    __syncthreads();
    *(s16x8*)&As[sr * LDSW + cg * 16]     = ra0;
    *(s16x8*)&As[sr * LDSW + cg * 16 + 8] = ra1;
    *(s16x8*)&Bs[srb * LDSW + cgb * 8]    = rb;
    if (k0 + 64 < FDIM) {                  // prefetch next chunk (overlaps MFMA)
      ra0 = *(const s16x8*)(pa + k0 + 64);
      ra1 = *(const s16x8*)(pa + k0 + 72);
      rb  = *(const s16x8*)(pb + k0 + 64);
    }
    __syncthreads();
#pragma unroll
    for (int koff = 0; koff < 64; koff += 32) {
      s16x8 af0 = *(s16x8*)&As[(wm + m16) * LDSW + koff + q * 8];
      s16x8 af1 = *(s16x8*)&As[(wm + 16 + m16) * LDSW + koff + q * 8];
      s16x8 bf0 = *(s16x8*)&Bs[(wn + m16) * LDSW + koff + q * 8];
      acc[0] = __builtin_amdgcn_mfma_f32_16x16x32_bf16(af0, bf0, acc[0], 0, 0, 0);
      acc[1] = __builtin_amdgcn_mfma_f32_16x16x32_bf16(af1, bf0, acc[1], 0, 0, 0);
    }
  }
  // epilogue: D map col(n)=lane&15, row(m)=q*4+reg; rows contiguous in PRBT/PCT
#pragma unroll
  for (int rt = 0; rt < 2; ++rt) {
    const int hn = bn + wn + m16;          // 0..511
    const int row0 = bm + wm + rt * 16 + q * 4;
    if (hn < 256) {
      const float bias = b1[hn];
      float4 v = make_float4(acc[rt][0] + bias, acc[rt][1] + bias,
                             acc[rt][2] + bias, acc[rt][3] + bias);
      *(float4*)&PRBT[hn * ROWS + row0] = v;
    } else {
      float4 v = make_float4(acc[rt][0], acc[rt][1], acc[rt][2], acc[rt][3]);
      *(float4*)&PCT[(hn - 256) * ROWS + row0] = v;
    }
  }
}

// ---------- K2: edge + 13-bit count/value histogram ----------
// tile 64(i) x 32(j), 512 threads (8 waves, 1 block/CU), 2x2 per thread; grid 256.
// f32x2 inner loop (v_pk_add/v_pk_fma); REGISTER-PREFETCHED staging: chunk k+1's
// global loads issue right after chunk k's LDS writes and fly under the 64-h
// compute phase (1 block/CU -> no cross-block hiding; this is the only cover).
__global__ __launch_bounds__(512) void k_edge(const float* __restrict__ PRBT,
                                              const float* __restrict__ PCT,
                                              const float* __restrict__ W2,
                                              const float* __restrict__ b2,
                                              float* __restrict__ edge,
                                              unsigned* __restrict__ gcount,
                                              float* __restrict__ gvsum) {
  const int b = blockIdx.z;
  const int i0 = blockIdx.y * 64, j0 = blockIdx.x * 32;
  const int t = threadIdx.x;
  __shared__ float prs[64][68];        // [h][i]
  __shared__ float pcs[64][36];        // [h][j]
  __shared__ float w2s[HDIM];
  __shared__ unsigned lhc[NBIN / 2];   // packed 2x16-bit counts (16 KB)
  __shared__ float lhv[NBIN];          // value sums (32 KB)
  if (t < HDIM) w2s[t] = W2[t];
#pragma unroll
  for (int i = 0; i < 2; ++i) ((uint4*)lhc)[t + i * 512] = make_uint4(0u, 0u, 0u, 0u);
#pragma unroll
  for (int i = 0; i < 4; ++i) ((float4*)lhv)[t + i * 512] = make_float4(0.f, 0.f, 0.f, 0.f);
  const float bias = b2[0];
  const int tmi = t >> 4, tnj = t & 15;     // i-pair 0..31, j-pair 0..15
  // staging geometry: prs rows hh and hh+32 share column ig ((t+512)>>4 == (t>>4)+32)
  const int hh = t >> 4, ig = t & 15;       // prs: [hh][ig*4], [hh+32][ig*4]
  const int hh2 = t >> 3, jg = t & 7;       // pcs: [hh2][jg*4]
  const float* pa0 = PRBT + hh * ROWS + b * NN + i0 + ig * 4;
  const float* pa1 = PRBT + (hh + 32) * ROWS + b * NN + i0 + ig * 4;
  const float* pc  = PCT + hh2 * ROWS + b * NN + j0 + jg * 4;
  f32x2 acc0 = {0.f, 0.f};                  // row ibase   : (j, j+1)
  f32x2 acc1 = {0.f, 0.f};                  // row ibase+1 : (j, j+1)
  // prologue: chunk 0 into registers
  float4 ra0 = *(const float4*)(pa0);
  float4 ra1 = *(const float4*)(pa1);
  float4 rc  = *(const float4*)(pc);
  for (int h0 = 0; h0 < HDIM; h0 += 64) {
    __syncthreads();                        // previous chunk's readers done
    *(float4*)&prs[hh][ig * 4]      = ra0;
    *(float4*)&prs[hh + 32][ig * 4] = ra1;
    *(float4*)&pcs[hh2][jg * 4]     = rc;
    if (h0 + 64 < HDIM) {                   // prefetch chunk k+1 (flies under compute)
      ra0 = *(const float4*)(pa0 + (h0 + 64) * ROWS);
      ra1 = *(const float4*)(pa1 + (h0 + 64) * ROWS);
      rc  = *(const float4*)(pc  + (h0 + 64) * ROWS);
    }
    __syncthreads();                        // writes visible
#pragma unroll 8
    for (int h = 0; h < 64; ++h) {
      const float w = w2s[h0 + h];
      const f32x2 a = *(const f32x2*)&prs[h][tmi * 2];
      const f32x2 c = *(const f32x2*)&pcs[h][tnj * 2];
      f32x2 x0 = c + a.x;                   // pk_add
      f32x2 x1 = c + a.y;
      x0.x = fmaxf(x0.x, 0.f); x0.y = fmaxf(x0.y, 0.f);
      x1.x = fmaxf(x1.x, 0.f); x1.y = fmaxf(x1.y, 0.f);
      acc0 += x0 * w;                       // pk_fma
      acc1 += x1 * w;
    }
  }
  // write edge + histogram (values in registers)
  const int ibase = i0 + tmi * 2, jbase = j0 + tnj * 2;
  float av[2][2] = {{acc0.x, acc0.y}, {acc1.x, acc1.y}};
#pragma unroll
  for (int i = 0; i < 2; ++i) {
    float2 v = make_float2(av[i][0] + bias, av[i][1] + bias);
    *(float2*)&edge[b * NSQ + (ibase + i) * NN + jbase] = v;
    float ex = __expf(v.x * 2.f), ey = __expf(v.y * 2.f);
    unsigned bx = fkey(v.x) >> 19, by = fkey(v.y) >> 19;
    atomicAdd(&lhc[bx >> 1], 1u << ((bx & 1) * 16));
    atomicAdd(&lhv[bx], ex);
    atomicAdd(&lhc[by >> 1], 1u << ((by & 1) * 16));
    atomicAdd(&lhv[by], ey);
  }
  __syncthreads();
  unsigned* gc = gcount + b * NBIN;
  float* gv = gvsum + b * NBIN;
#pragma unroll
  for (int i = 0; i < 8; ++i) {
    const int idx = t + i * 512;
    unsigned wv = lhc[idx];
    if (wv) {
      unsigned lo = wv & 0xFFFFu, hi = wv >> 16;
      if (lo) atomicAdd(&gc[2 * idx], lo);
      if (hi) atomicAdd(&gc[2 * idx + 1], hi);
    }
  }
#pragma unroll
  for (int i = 0; i < 16; ++i) {
    const int idx = t + i * 512;
    float vv = lhv[idx];
    if (vv != 0.f) atomicAdd(&gv[idx], vv);
  }
}

// ---------- K3: scan (inline) + soft + causal + conf ----------
__global__ __launch_bounds__(256) void k_out(const float* __restrict__ edge,
                                             const unsigned* __restrict__ gcount,
                                             const float* __restrict__ gvsum,
                                             float* __restrict__ soft,
                                             float* __restrict__ causal,
                                             float* __restrict__ conf) {
  const int b = blockIdx.y;
  const int t = threadIdx.x;
  __shared__ unsigned S[256];
  __shared__ float V[256];
  __shared__ unsigned ou[1];
  __shared__ float of[3];
  const unsigned* hc = gcount + b * NBIN;
  const float* hv = gvsum + b * NBIN;
  unsigned cs = 0; float vs = 0.f;
  {
    const uint4* hc4 = (const uint4*)(hc + t * 32);
    const float4* hv4 = (const float4*)(hv + t * 32);
#pragma unroll
    for (int i = 0; i < 8; ++i) {
      uint4 c = hc4[i];
      float4 v = hv4[i];
      cs += c.x + c.y + c.z + c.w;
      vs += v.x + v.y + v.z + v.w;
    }
  }
  S[t] = cs; V[t] = vs;
  __syncthreads();
  for (int off = 1; off < 256; off <<= 1) {     // inclusive suffix sums
    unsigned su = (t + off < 256) ? S[t + off] : 0u;
    float vu = (t + off < 256) ? V[t + off] : 0.f;
    __syncthreads();
    S[t] += su; V[t] += vu;
    __syncthreads();
  }
  if (t == 0) of[2] = V[0];                      // Z = total exp sum
  const int above = (int)(S[t] - cs);
  if (above < KSEL && (int)S[t] >= KSEL) {       // exactly one thread
    int cum = above;
    float vcum = V[t] - vs;
    for (int i = 31; i >= 0; --i) {
      unsigned c = hc[t * 32 + i];
      float v = hv[t * 32 + i];
      cum += (int)c;
      if (cum >= KSEL) { ou[0] = (unsigned)(t * 32 + i); of[0] = vcum; of[1] = v; break; }
      vcum += v;
    }
  }
  __syncthreads();
  const float th = finv(ou[0] << 19);            // 13-bit truncated threshold
  const float Z = of[2];
  const float invZ = 1.f / Z;
  const float msum = (of[0] + of[1]) * invZ;     // masked soft sum (bin-exact)
  const float invD = 1.f / (msum + 1e-12f);
  const int off = b * NSQ + blockIdx.x * 2048 + t * 8;
#pragma unroll
  for (int i = 0; i < 8; i += 4) {
    float4 v = *(const float4*)&edge[off + i];
    float4 o = make_float4(__expf(v.x * 2.f) * invZ, __expf(v.y * 2.f) * invZ,
                           __expf(v.z * 2.f) * invZ, __expf(v.w * 2.f) * invZ);
    *(float4*)&soft[off + i] = o;
    float cx = v.x >= th ? o.x * invD : 0.f;
    float cy = v.y >= th ? o.y * invD : 0.f;
    float cz = v.z >= th ? o.z * invD : 0.f;
    float cw = v.w >= th ? o.w * invD : 0.f;
    *(float4*)&causal[off + i] = make_float4(cx, cy, cz, cw);
    *(float4*)&conf[off + i]   = make_float4(1.f - cx, 1.f - cy, 1.f - cz, 1.f - cw);
  }
}

extern "C" void kernel_launch(void* const* d_in, const int* in_sizes, int n_in,
                              void* d_out, int out_size, void* d_ws, size_t ws_size,
                              hipStream_t stream) {
  const float* x  = (const float*)d_in[0];
  const float* W1 = (const float*)d_in[1];
  const float* b1 = (const float*)d_in[2];
  const float* W2 = (const float*)d_in[3];
  const float* b2 = (const float*)d_in[4];

  float* out = (float*)d_out;
  float* causal = out;
  float* conf   = out + 1 * 524288;
  float* edge   = out + 2 * 524288;
  float* soft   = out + 3 * 524288;

  float* ws = (float*)d_ws;
  float*          PRBT   = ws;                                // 524288 floats
  float*          PCT    = ws + 524288;                       // 524288 floats
  unsigned short* XB     = (unsigned short*)(ws + 1048576);   // 2097152 bf16
  unsigned short* W1B    = (unsigned short*)(ws + 2097152);   // 524288 bf16
  unsigned*       gcount = (unsigned*)(ws + 2359296);         // 8*8192 uints
  float*          gvsum  = (float*)(ws + 2424832);            // 8*8192 floats (zero: 131072 words)

  k_prep<<<1408, 256, 0, stream>>>(x, W1, XB, W1B, gcount);
  k_gemm<<<dim3(32, 16), 256, 0, stream>>>(XB, W1B, b1, PRBT, PCT);
  k_edge<<<dim3(8, 4, 8), 512, 0, stream>>>(PRBT, PCT, W2, b2, edge, gcount, gvsum);
  k_out<<<dim3(32, 8), 256, 0, stream>>>(edge, gcount, gvsum, soft, causal, conf);
}